// Round 4
// baseline (393.732 us; speedup 1.0000x reference)
//
#include <hip/hip_runtime.h>

// Problem constants
#define B   16
#define C   32
#define T2  8
#define H   256
#define W   256
#define NF  (B * T2 * H * W)   // 8,388,608 floats per [B,T2,H,W] field (32 MiB)

// Two launch plans chosen by ws_size (constant per harness run -> capture-safe):
//  FAST (ws >= 4 fields = 128 MiB): one x-pass computes all 6 weighted fields.
//    ws: [0,NF)=F3->A->v2->V  [NF,2NF)=F2  [2NF,3NF)=F3p->Ap  [3NF,4NF)=F2p->Bp
//  SAFE (ws >= 2 fields = 64 MiB): linear tree fully, then recompute cherry
//    weights with a second x-pass into the same 2 fields.
// d_out: out[b,0..7] pre-filled with W1, out[b,8..15] with W1p; both are
// multiplied in place by the final kernels.

__device__ __forceinline__ float wave_incl_scan(float s, int lane) {
#pragma unroll
  for (int d = 1; d < 64; d <<= 1) {
    float n = __shfl_up(s, (unsigned)d, 64);
    if (lane >= d) s += n;
  }
  return s;
}

// ---------------------------------------------------------------------------
// K1a: all 6 contractions in one x-pass (FAST path).
// ---------------------------------------------------------------------------
__global__ __launch_bounds__(256) void k_weight6(
    const float* __restrict__ x,
    const float* __restrict__ a1,  const float* __restrict__ a2,
    const float* __restrict__ a3,  const float* __restrict__ a1p,
    const float* __restrict__ a2p, const float* __restrict__ a3p,
    float* __restrict__ ws, float* __restrict__ out) {
  int pix = blockIdx.x * 256 + threadIdx.x;   // [0, B*H*W)
  int b  = pix >> 16;                          // H*W = 65536
  int hw = pix & 65535;
  const float* xb = x + (size_t)(b * C) * 65536 + hw;

  float acc1[T2] = {}, acc2[T2] = {}, acc3[T2] = {};
  float acc1p[T2] = {}, acc2p[T2] = {}, acc3p[T2] = {};

#pragma unroll
  for (int c = 0; c < C; ++c) {
    float xv = xb[(size_t)c * 65536];
#pragma unroll
    for (int t = 0; t < T2; ++t) {
      acc3[t]  = fmaf(a3 [t * C + c], xv, acc3[t]);
      acc2[t]  = fmaf(a2 [t * C + c], xv, acc2[t]);
      acc1[t]  = fmaf(a1 [t * C + c], xv, acc1[t]);
      acc3p[t] = fmaf(a3p[t * C + c], xv, acc3p[t]);
      acc2p[t] = fmaf(a2p[t * C + c], xv, acc2p[t]);
      acc1p[t] = fmaf(a1p[t * C + c], xv, acc1p[t]);
    }
  }

#pragma unroll
  for (int t = 0; t < T2; ++t) {
    size_t so = ((size_t)(b * T2 + t) << 16) + hw;
    ws[so]               = acc3[t];
    ws[(size_t)NF + so]  = acc2[t];
    ws[2ull * NF + so]   = acc3p[t];
    ws[3ull * NF + so]   = acc2p[t];
    out[((size_t)(b * 16 + t)     << 16) + hw] = acc1[t];
    out[((size_t)(b * 16 + 8 + t) << 16) + hw] = acc1p[t];
  }
}

// ---------------------------------------------------------------------------
// K1b: 3 contractions (one tree family) in one x-pass (SAFE path).
// aA -> out[b, outoff+t], aB -> ws0, aC -> ws1.
// ---------------------------------------------------------------------------
__global__ __launch_bounds__(256) void k_weight3(
    const float* __restrict__ x,
    const float* __restrict__ aA, const float* __restrict__ aB,
    const float* __restrict__ aC,
    float* __restrict__ ws0, float* __restrict__ ws1,
    float* __restrict__ out, int outoff) {
  int pix = blockIdx.x * 256 + threadIdx.x;
  int b  = pix >> 16;
  int hw = pix & 65535;
  const float* xb = x + (size_t)(b * C) * 65536 + hw;

  float accA[T2] = {}, accB[T2] = {}, accC[T2] = {};

#pragma unroll
  for (int c = 0; c < C; ++c) {
    float xv = xb[(size_t)c * 65536];
#pragma unroll
    for (int t = 0; t < T2; ++t) {
      accA[t] = fmaf(aA[t * C + c], xv, accA[t]);
      accB[t] = fmaf(aB[t * C + c], xv, accB[t]);
      accC[t] = fmaf(aC[t * C + c], xv, accC[t]);
    }
  }

#pragma unroll
  for (int t = 0; t < T2; ++t) {
    size_t so = ((size_t)(b * T2 + t) << 16) + hw;
    ws0[so] = accB[t];
    ws1[so] = accC[t];
    out[((size_t)(b * 16 + outoff + t) << 16) + hw] = accA[t];
  }
}

// ---------------------------------------------------------------------------
// Strict REVERSE cumsum along h, in place. blockIdx.x = slice (one [H,W]
// image), threadIdx.x = w column. Coalesced across w.
// ---------------------------------------------------------------------------
__global__ __launch_bounds__(256) void k_colscan_rev(float* __restrict__ base_) {
  float* base = base_ + ((size_t)blockIdx.x << 16) + threadIdx.x;
  float run = 0.f;
#pragma unroll 8
  for (int h = 255; h >= 0; --h) {
    float v = base[h << 8];
    base[h << 8] = run;               // strict: sum over h' > h
    run += v;
  }
}

// Strict FORWARD cumsum along h, in place.
__global__ __launch_bounds__(256) void k_colscan_fwd(float* __restrict__ base_) {
  float* base = base_ + ((size_t)blockIdx.x << 16) + threadIdx.x;
  float run = 0.f;
#pragma unroll 8
  for (int h = 0; h < 256; ++h) {
    float v = base[h << 8];
    base[h << 8] = run;               // strict: sum over h' < h
    run += v;
  }
}

// ---------------------------------------------------------------------------
// v2 = F2 * (strict fwd row-scan of A); A in wsA (overwritten), F2 in wsB.
// One wave per 256-elem row; float4 per lane + 64-lane shuffle scan.
// ---------------------------------------------------------------------------
__global__ __launch_bounds__(256) void k_row_v2(float* __restrict__ wsA,
                                                const float* __restrict__ wsB) {
  int lane = threadIdx.x & 63;
  int r = blockIdx.x * 4 + (threadIdx.x >> 6);          // row [0, 32768)
  float4* arow = (float4*)(wsA + (size_t)r * 256);
  const float4* brow = (const float4*)(wsB + (size_t)r * 256);

  float4 a = arow[lane];
  float s = a.x + a.y + a.z + a.w;
  float incl = wave_incl_scan(s, lane);
  float excl = incl - s;
  float e0 = excl, e1 = e0 + a.x, e2 = e1 + a.y, e3 = e2 + a.z;

  float4 bq = brow[lane];
  float4 o;
  o.x = bq.x * e0; o.y = bq.y * e1; o.z = bq.z * e2; o.w = bq.w * e3;
  arow[lane] = o;
}

// ---------------------------------------------------------------------------
// out[b,t] = W1 (already in out) * (strict REVERSE row-scan of V).
// ---------------------------------------------------------------------------
__global__ __launch_bounds__(256) void k_final_linear(const float* __restrict__ wsV,
                                                      float* __restrict__ out) {
  int lane = threadIdx.x & 63;
  int r = blockIdx.x * 4 + (threadIdx.x >> 6);          // row [0, 32768)
  const float4* vrow = (const float4*)(wsV + (size_t)r * 256);
  float4 a = vrow[lane];
  float s = a.x + a.y + a.z + a.w;
  float incl = wave_incl_scan(s, lane);
  float excl = incl - s;
  float total = __shfl(incl, 63, 64);
  float r0 = total - excl - a.x;                        // sum over w' > w
  float r1 = r0 - a.y;
  float r2 = r1 - a.z;
  float r3 = r2 - a.w;

  int b = r >> 11, t = (r >> 8) & 7, h = r & 255;
  float* orow = out + ((size_t)((b * 16 + t) * 256 + h)) * 256;
  float4 f = ((const float4*)orow)[lane];
  float4 o;
  o.x = f.x * r0; o.y = f.y * r1; o.z = f.z * r2; o.w = f.w * r3;
  ((float4*)orow)[lane] = o;
}

// ---------------------------------------------------------------------------
// out[b,8+t] = W1p (already in out) * fwdstrict_w(Ap) * revstrict_w(Bp).
// ---------------------------------------------------------------------------
__global__ __launch_bounds__(256) void k_cherry(const float* __restrict__ wsAp,
                                                const float* __restrict__ wsBp,
                                                float* __restrict__ out) {
  int lane = threadIdx.x & 63;
  int r = blockIdx.x * 4 + (threadIdx.x >> 6);          // row [0, 32768)
  const float4* ap = (const float4*)(wsAp + (size_t)r * 256);
  const float4* bp = (const float4*)(wsBp + (size_t)r * 256);
  float4 a  = ap[lane];
  float4 bq = bp[lane];
  float sa = a.x + a.y + a.z + a.w;
  float sb = bq.x + bq.y + bq.z + bq.w;
  float ia = wave_incl_scan(sa, lane);
  float ib = wave_incl_scan(sb, lane);
  float ea = ia - sa;
  float eb = ib - sb;
  float tb = __shfl(ib, 63, 64);

  float fa0 = ea, fa1 = fa0 + a.x, fa2 = fa1 + a.y, fa3 = fa2 + a.z;  // w' < w
  float rb0 = tb - eb - bq.x;                                          // w' > w
  float rb1 = rb0 - bq.y;
  float rb2 = rb1 - bq.z;
  float rb3 = rb2 - bq.w;

  int b = r >> 11, t = (r >> 8) & 7, h = r & 255;
  float* orow = out + ((size_t)((b * 16 + 8 + t) * 256 + h)) * 256;
  float4 f = ((const float4*)orow)[lane];
  float4 o;
  o.x = f.x * fa0 * rb0;
  o.y = f.y * fa1 * rb1;
  o.z = f.z * fa2 * rb2;
  o.w = f.w * fa3 * rb3;
  ((float4*)orow)[lane] = o;
}

// ---------------------------------------------------------------------------
extern "C" void kernel_launch(void* const* d_in, const int* in_sizes, int n_in,
                              void* d_out, int out_size, void* d_ws, size_t ws_size,
                              hipStream_t stream) {
  const float* x   = (const float*)d_in[0];
  const float* a1  = (const float*)d_in[1];
  const float* a2  = (const float*)d_in[2];
  const float* a3  = (const float*)d_in[3];
  const float* a1p = (const float*)d_in[4];
  const float* a2p = (const float*)d_in[5];
  const float* a3p = (const float*)d_in[6];
  float* out = (float*)d_out;
  float* ws  = (float*)d_ws;

  const size_t field_bytes = (size_t)NF * 4;

  if (ws_size >= 4 * field_bytes) {
    // FAST: one x-pass, 4 scratch fields.
    k_weight6<<<4096, 256, 0, stream>>>(x, a1, a2, a3, a1p, a2p, a3p, ws, out);
    k_colscan_rev<<<128, 256, 0, stream>>>(ws);              // F3 -> A
    k_colscan_rev<<<256, 256, 0, stream>>>(ws + 2ull * NF);  // F3p,F2p -> Ap,Bp
    k_row_v2<<<8192, 256, 0, stream>>>(ws, ws + NF);         // v2 = F2*fwd_w(A)
    k_colscan_fwd<<<128, 256, 0, stream>>>(ws);              // v2 -> V
    k_final_linear<<<8192, 256, 0, stream>>>(ws, out);       // linear
    k_cherry<<<8192, 256, 0, stream>>>(ws + 2ull * NF, ws + 3ull * NF, out);
  } else {
    // SAFE: 2 scratch fields (64 MiB), two x-passes.
    float* ws0 = ws;
    float* ws1 = ws + NF;
    // Linear tree: W1->out[:,0..7], F3->ws0, F2->ws1.
    k_weight3<<<4096, 256, 0, stream>>>(x, a1, a3, a2, ws0, ws1, out, 0);
    k_colscan_rev<<<128, 256, 0, stream>>>(ws0);             // F3 -> A
    k_row_v2<<<8192, 256, 0, stream>>>(ws0, ws1);            // v2
    k_colscan_fwd<<<128, 256, 0, stream>>>(ws0);             // v2 -> V
    k_final_linear<<<8192, 256, 0, stream>>>(ws0, out);
    // Cherry tree: W1p->out[:,8..15], F3p->ws0, F2p->ws1.
    k_weight3<<<4096, 256, 0, stream>>>(x, a1p, a3p, a2p, ws0, ws1, out, 8);
    k_colscan_rev<<<256, 256, 0, stream>>>(ws0);             // both fields (contiguous)
    k_cherry<<<8192, 256, 0, stream>>>(ws0, ws1, out);
  }
}

// Round 7
// 338.706 us; speedup vs baseline: 1.1625x; 1.1625x over previous
//
#include <hip/hip_runtime.h>

// Problem constants
#define B   16
#define C   32
#define T2  8
#define H   256
#define W   256
#define NF  (B * T2 * H * W)     // 8,388,608 floats per [B,T2,H,W] field (32 MiB)
#define NCH 8                    // h-chunks per image
#define CH  32                   // rows per chunk
#define SUMSZ (B * T2 * NCH * W) // 262,144 floats per chunk-sum array (1 MiB)

// Paths by ws_size (constant per run -> capture-safe):
//  FAST2 (ws >= 4 fields + 4 sum arrays): fused two-phase chunked scans.
//  FAST  (ws >= 4 fields): round-4 verified pipeline (serial col-scans).
//  SAFE  (ws >= 2 fields): two x-passes.
// ws (FAST2): [0,NF)=F3->v2  [NF,2NF)=F2  [2NF,3NF)=F3p  [3NF,4NF)=F2p
//             [4NF..) sums: S3 | S3p | S2p | Sv2 (SUMSZ floats each)
// d_out: out[b,0..7]=W1, out[b,8..15]=W1p (pre-filled by k_weight6, multiplied
// in place by the final kernels).

__device__ __forceinline__ float wave_incl_scan(float s, int lane) {
#pragma unroll
  for (int d = 1; d < 64; d <<= 1) {
    float n = __shfl_up(s, (unsigned)d, 64);
    if (lane >= d) s += n;
  }
  return s;
}

// ---------------------------------------------------------------------------
// K1: all 6 contractions in one x-pass (unchanged from round 4; verified).
// ---------------------------------------------------------------------------
__global__ __launch_bounds__(256) void k_weight6(
    const float* __restrict__ x,
    const float* __restrict__ a1,  const float* __restrict__ a2,
    const float* __restrict__ a3,  const float* __restrict__ a1p,
    const float* __restrict__ a2p, const float* __restrict__ a3p,
    float* __restrict__ ws, float* __restrict__ out) {
  int pix = blockIdx.x * 256 + threadIdx.x;   // [0, B*H*W)
  int b  = pix >> 16;                          // H*W = 65536
  int hw = pix & 65535;
  const float* xb = x + (size_t)(b * C) * 65536 + hw;

  float acc1[T2] = {}, acc2[T2] = {}, acc3[T2] = {};
  float acc1p[T2] = {}, acc2p[T2] = {}, acc3p[T2] = {};

#pragma unroll
  for (int c = 0; c < C; ++c) {
    float xv = xb[(size_t)c * 65536];
#pragma unroll
    for (int t = 0; t < T2; ++t) {
      acc3[t]  = fmaf(a3 [t * C + c], xv, acc3[t]);
      acc2[t]  = fmaf(a2 [t * C + c], xv, acc2[t]);
      acc1[t]  = fmaf(a1 [t * C + c], xv, acc1[t]);
      acc3p[t] = fmaf(a3p[t * C + c], xv, acc3p[t]);
      acc2p[t] = fmaf(a2p[t * C + c], xv, acc2p[t]);
      acc1p[t] = fmaf(a1p[t * C + c], xv, acc1p[t]);
    }
  }

#pragma unroll
  for (int t = 0; t < T2; ++t) {
    size_t so = ((size_t)(b * T2 + t) << 16) + hw;
    ws[so]               = acc3[t];
    ws[(size_t)NF + so]  = acc2[t];
    ws[2ull * NF + so]   = acc3p[t];
    ws[3ull * NF + so]   = acc2p[t];
    out[((size_t)(b * 16 + t)     << 16) + hw] = acc1[t];
    out[((size_t)(b * 16 + 8 + t) << 16) + hw] = acc1p[t];
  }
}

// ---------------------------------------------------------------------------
// K1b: per-chunk column sums for fields F3 (f=0), F3p (f=1), F2p (f=2).
// S[f][slice][chunk][w] = sum_{h in chunk} field[slice][h][w].
// ---------------------------------------------------------------------------
__global__ __launch_bounds__(256) void k_chunksums(float* __restrict__ ws) {
  int f    = blockIdx.x >> 10;          // 0..2
  int bid  = blockIdx.x & 1023;
  int slice = bid >> 3, chunk = bid & 7;
  int w = threadIdx.x;
  const size_t fieldOff[3] = {0, 2ull * NF, 3ull * NF};
  const float* base = ws + fieldOff[f] + ((size_t)slice << 16) + (size_t)(chunk * CH) * W + w;
  float s = 0.f;
#pragma unroll
  for (int h = 0; h < CH; ++h) s += base[h * W];
  float* sums = ws + 4ull * NF + (size_t)f * SUMSZ;
  sums[(size_t)(slice * NCH + chunk) * W + w] = s;
}

// ---------------------------------------------------------------------------
// K2: fused linear-mid. Per (slice, chunk) block:
//  A = rev-strict-h scan of F3 (seeded with cross-chunk offset) -> LDS tile
//  v2 = F2 * fwd-strict-w(A) -> written in place over F3
//  Sv2[slice][chunk][w] = column sums of v2 over this chunk.
// ---------------------------------------------------------------------------
__global__ __launch_bounds__(256) void k_linear_mid(float* __restrict__ ws) {
  __shared__ float tile[CH][W];
  __shared__ float colpart[4][W];
  int slice = blockIdx.x >> 3, chunk = blockIdx.x & 7;
  int tid = threadIdx.x, lane = tid & 63, wv = tid >> 6;

  const float* S3 = ws + 4ull * NF;                 // [slice][chunk][w]
  float* Sv2      = ws + 4ull * NF + 3ull * SUMSZ;
  float* fbase  = ws + ((size_t)slice << 16) + (size_t)(chunk * CH) * W;          // F3 tile / v2 out
  const float* f2base = ws + (size_t)NF + ((size_t)slice << 16) + (size_t)(chunk * CH) * W;

  // Phase A: column walk (thread = w column), rev-strict, seeded with offset.
  {
    int w = tid;
    float run = 0.f;
#pragma unroll
    for (int c = 0; c < NCH; ++c)
      if (c > chunk) run += S3[(size_t)(slice * NCH + c) * W + w];
#pragma unroll
    for (int h = CH - 1; h >= 0; --h) {
      float v = fbase[(size_t)h * W + w];
      tile[h][w] = run;                 // strict: excludes row h itself
      run += v;
    }
  }
  __syncthreads();

  // Phase B: wave per row (8 rows per wave): fwd-strict-w scan, *F2, colsum.
  float4 cs = {0.f, 0.f, 0.f, 0.f};
#pragma unroll
  for (int i = 0; i < 8; ++i) {
    int h = wv * 8 + i;
    float4 a = *(const float4*)&tile[h][lane * 4];
    float s = a.x + a.y + a.z + a.w;
    float incl = wave_incl_scan(s, lane);
    float excl = incl - s;
    float e0 = excl, e1 = e0 + a.x, e2 = e1 + a.y, e3 = e2 + a.z;
    float4 f = *(const float4*)&f2base[(size_t)h * W + lane * 4];
    float4 o;
    o.x = f.x * e0; o.y = f.y * e1; o.z = f.z * e2; o.w = f.w * e3;
    *(float4*)&fbase[(size_t)h * W + lane * 4] = o;   // v2 in place
    cs.x += o.x; cs.y += o.y; cs.z += o.z; cs.w += o.w;
  }
  *(float4*)&colpart[wv][lane * 4] = cs;
  __syncthreads();
  {
    int w = tid;
    float sv = colpart[0][w] + colpart[1][w] + colpart[2][w] + colpart[3][w];
    Sv2[(size_t)(slice * NCH + chunk) * W + w] = sv;
  }
}

// ---------------------------------------------------------------------------
// K3: fused linear-final. V = fwd-strict-h scan of v2 (seeded); then
// out[b,t] = W1(in out) * rev-strict-w(V).
// ---------------------------------------------------------------------------
__global__ __launch_bounds__(256) void k_linear_fin(const float* __restrict__ ws,
                                                    float* __restrict__ out) {
  __shared__ float tile[CH][W];
  int slice = blockIdx.x >> 3, chunk = blockIdx.x & 7;
  int tid = threadIdx.x, lane = tid & 63, wv = tid >> 6;

  const float* Sv2 = ws + 4ull * NF + 3ull * SUMSZ;
  const float* vbase = ws + ((size_t)slice << 16) + (size_t)(chunk * CH) * W;

  {
    int w = tid;
    float run = 0.f;
#pragma unroll
    for (int c = 0; c < NCH; ++c)
      if (c < chunk) run += Sv2[(size_t)(slice * NCH + c) * W + w];
#pragma unroll
    for (int h = 0; h < CH; ++h) {
      float v = vbase[(size_t)h * W + w];
      tile[h][w] = run;                 // strict: excludes row h
      run += v;
    }
  }
  __syncthreads();

  int b = slice >> 3, t = slice & 7;
  float* obase = out + ((size_t)(b * 16 + t) << 16) + (size_t)(chunk * CH) * W;
#pragma unroll
  for (int i = 0; i < 8; ++i) {
    int h = wv * 8 + i;
    float4 a = *(const float4*)&tile[h][lane * 4];
    float s = a.x + a.y + a.z + a.w;
    float incl = wave_incl_scan(s, lane);
    float excl = incl - s;
    float total = __shfl(incl, 63, 64);
    float r0 = total - excl - a.x;      // sum over w' > w
    float r1 = r0 - a.y, r2 = r1 - a.z, r3 = r2 - a.w;
    float4 f = *(const float4*)&obase[(size_t)h * W + lane * 4];
    float4 o;
    o.x = f.x * r0; o.y = f.y * r1; o.z = f.z * r2; o.w = f.w * r3;
    *(float4*)&obase[(size_t)h * W + lane * 4] = o;
  }
}

// ---------------------------------------------------------------------------
// K4: fused cherry. Ap = revh(F3p), Bp = revh(F2p) (both seeded);
// out[b,8+t] = W1p(in out) * fwd-strict-w(Ap) * rev-strict-w(Bp).
// ---------------------------------------------------------------------------
__global__ __launch_bounds__(256) void k_cherry2(const float* __restrict__ ws,
                                                 float* __restrict__ out) {
  __shared__ float tA[CH][W];
  __shared__ float tB[CH][W];
  int slice = blockIdx.x >> 3, chunk = blockIdx.x & 7;
  int tid = threadIdx.x, lane = tid & 63, wv = tid >> 6;

  const float* S3p = ws + 4ull * NF + 1ull * SUMSZ;
  const float* S2p = ws + 4ull * NF + 2ull * SUMSZ;
  const float* abase = ws + 2ull * NF + ((size_t)slice << 16) + (size_t)(chunk * CH) * W;
  const float* bbase = ws + 3ull * NF + ((size_t)slice << 16) + (size_t)(chunk * CH) * W;

  {
    int w = tid;
    float runA = 0.f, runB = 0.f;
#pragma unroll
    for (int c = 0; c < NCH; ++c)
      if (c > chunk) {
        runA += S3p[(size_t)(slice * NCH + c) * W + w];
        runB += S2p[(size_t)(slice * NCH + c) * W + w];
      }
#pragma unroll
    for (int h = CH - 1; h >= 0; --h) {
      float va = abase[(size_t)h * W + w];
      float vb = bbase[(size_t)h * W + w];
      tA[h][w] = runA; runA += va;
      tB[h][w] = runB; runB += vb;
    }
  }
  __syncthreads();

  int b = slice >> 3, t = slice & 7;
  float* obase = out + ((size_t)(b * 16 + 8 + t) << 16) + (size_t)(chunk * CH) * W;
#pragma unroll
  for (int i = 0; i < 8; ++i) {
    int h = wv * 8 + i;
    float4 a = *(const float4*)&tA[h][lane * 4];
    float4 bq = *(const float4*)&tB[h][lane * 4];
    float sa = a.x + a.y + a.z + a.w;
    float sb = bq.x + bq.y + bq.z + bq.w;
    float ia = wave_incl_scan(sa, lane);
    float ib = wave_incl_scan(sb, lane);
    float ea = ia - sa;
    float eb = ib - sb;
    float tb = __shfl(ib, 63, 64);
    float fa0 = ea, fa1 = fa0 + a.x, fa2 = fa1 + a.y, fa3 = fa2 + a.z;  // w'<w
    float rb0 = tb - eb - bq.x;                                          // w'>w
    float rb1 = rb0 - bq.y, rb2 = rb1 - bq.z, rb3 = rb2 - bq.w;
    float4 f = *(const float4*)&obase[(size_t)h * W + lane * 4];
    float4 o;
    o.x = f.x * fa0 * rb0;
    o.y = f.y * fa1 * rb1;
    o.z = f.z * fa2 * rb2;
    o.w = f.w * fa3 * rb3;
    *(float4*)&obase[(size_t)h * W + lane * 4] = o;
  }
}

// ======================= round-4 fallback kernels ==========================
__global__ __launch_bounds__(256) void k_weight3(
    const float* __restrict__ x,
    const float* __restrict__ aA, const float* __restrict__ aB,
    const float* __restrict__ aC,
    float* __restrict__ ws0, float* __restrict__ ws1,
    float* __restrict__ out, int outoff) {
  int pix = blockIdx.x * 256 + threadIdx.x;
  int b  = pix >> 16;
  int hw = pix & 65535;
  const float* xb = x + (size_t)(b * C) * 65536 + hw;
  float accA[T2] = {}, accB[T2] = {}, accC[T2] = {};
#pragma unroll
  for (int c = 0; c < C; ++c) {
    float xv = xb[(size_t)c * 65536];
#pragma unroll
    for (int t = 0; t < T2; ++t) {
      accA[t] = fmaf(aA[t * C + c], xv, accA[t]);
      accB[t] = fmaf(aB[t * C + c], xv, accB[t]);
      accC[t] = fmaf(aC[t * C + c], xv, accC[t]);
    }
  }
#pragma unroll
  for (int t = 0; t < T2; ++t) {
    size_t so = ((size_t)(b * T2 + t) << 16) + hw;
    ws0[so] = accB[t];
    ws1[so] = accC[t];
    out[((size_t)(b * 16 + outoff + t) << 16) + hw] = accA[t];
  }
}

__global__ __launch_bounds__(256) void k_colscan_rev(float* __restrict__ base_) {
  float* base = base_ + ((size_t)blockIdx.x << 16) + threadIdx.x;
  float run = 0.f;
#pragma unroll 8
  for (int h = 255; h >= 0; --h) {
    float v = base[h << 8];
    base[h << 8] = run;
    run += v;
  }
}

__global__ __launch_bounds__(256) void k_colscan_fwd(float* __restrict__ base_) {
  float* base = base_ + ((size_t)blockIdx.x << 16) + threadIdx.x;
  float run = 0.f;
#pragma unroll 8
  for (int h = 0; h < 256; ++h) {
    float v = base[h << 8];
    base[h << 8] = run;
    run += v;
  }
}

__global__ __launch_bounds__(256) void k_row_v2(float* __restrict__ wsA,
                                                const float* __restrict__ wsB) {
  int lane = threadIdx.x & 63;
  int r = blockIdx.x * 4 + (threadIdx.x >> 6);
  float4* arow = (float4*)(wsA + (size_t)r * 256);
  const float4* brow = (const float4*)(wsB + (size_t)r * 256);
  float4 a = arow[lane];
  float s = a.x + a.y + a.z + a.w;
  float incl = wave_incl_scan(s, lane);
  float excl = incl - s;
  float e0 = excl, e1 = e0 + a.x, e2 = e1 + a.y, e3 = e2 + a.z;
  float4 bq = brow[lane];
  float4 o;
  o.x = bq.x * e0; o.y = bq.y * e1; o.z = bq.z * e2; o.w = bq.w * e3;
  arow[lane] = o;
}

__global__ __launch_bounds__(256) void k_final_linear(const float* __restrict__ wsV,
                                                      float* __restrict__ out) {
  int lane = threadIdx.x & 63;
  int r = blockIdx.x * 4 + (threadIdx.x >> 6);
  const float4* vrow = (const float4*)(wsV + (size_t)r * 256);
  float4 a = vrow[lane];
  float s = a.x + a.y + a.z + a.w;
  float incl = wave_incl_scan(s, lane);
  float excl = incl - s;
  float total = __shfl(incl, 63, 64);
  float r0 = total - excl - a.x;
  float r1 = r0 - a.y, r2 = r1 - a.z, r3 = r2 - a.w;
  int b = r >> 11, t = (r >> 8) & 7, h = r & 255;
  float* orow = out + ((size_t)((b * 16 + t) * 256 + h)) * 256;
  float4 f = ((const float4*)orow)[lane];
  float4 o;
  o.x = f.x * r0; o.y = f.y * r1; o.z = f.z * r2; o.w = f.w * r3;
  ((float4*)orow)[lane] = o;
}

__global__ __launch_bounds__(256) void k_cherry(const float* __restrict__ wsAp,
                                                const float* __restrict__ wsBp,
                                                float* __restrict__ out) {
  int lane = threadIdx.x & 63;
  int r = blockIdx.x * 4 + (threadIdx.x >> 6);
  const float4* ap = (const float4*)(wsAp + (size_t)r * 256);
  const float4* bp = (const float4*)(wsBp + (size_t)r * 256);
  float4 a  = ap[lane];
  float4 bq = bp[lane];
  float sa = a.x + a.y + a.z + a.w;
  float sb = bq.x + bq.y + bq.z + bq.w;
  float ia = wave_incl_scan(sa, lane);
  float ib = wave_incl_scan(sb, lane);
  float ea = ia - sa;
  float eb = ib - sb;
  float tb = __shfl(ib, 63, 64);
  float fa0 = ea, fa1 = fa0 + a.x, fa2 = fa1 + a.y, fa3 = fa2 + a.z;
  float rb0 = tb - eb - bq.x;
  float rb1 = rb0 - bq.y, rb2 = rb1 - bq.z, rb3 = rb2 - bq.w;
  int b = r >> 11, t = (r >> 8) & 7, h = r & 255;
  float* orow = out + ((size_t)((b * 16 + 8 + t) * 256 + h)) * 256;
  float4 f = ((const float4*)orow)[lane];
  float4 o;
  o.x = f.x * fa0 * rb0;
  o.y = f.y * fa1 * rb1;
  o.z = f.z * fa2 * rb2;
  o.w = f.w * fa3 * rb3;
  ((float4*)orow)[lane] = o;
}

// ---------------------------------------------------------------------------
extern "C" void kernel_launch(void* const* d_in, const int* in_sizes, int n_in,
                              void* d_out, int out_size, void* d_ws, size_t ws_size,
                              hipStream_t stream) {
  const float* x   = (const float*)d_in[0];
  const float* a1  = (const float*)d_in[1];
  const float* a2  = (const float*)d_in[2];
  const float* a3  = (const float*)d_in[3];
  const float* a1p = (const float*)d_in[4];
  const float* a2p = (const float*)d_in[5];
  const float* a3p = (const float*)d_in[6];
  float* out = (float*)d_out;
  float* ws  = (float*)d_ws;

  const size_t field_bytes = (size_t)NF * 4;
  const size_t need_fast2  = 4 * field_bytes + 4ull * SUMSZ * 4;

  if (ws_size >= need_fast2) {
    // FAST2: fused two-phase chunked scans.
    k_weight6<<<4096, 256, 0, stream>>>(x, a1, a2, a3, a1p, a2p, a3p, ws, out);
    k_chunksums<<<3072, 256, 0, stream>>>(ws);
    k_linear_mid<<<1024, 256, 0, stream>>>(ws);
    k_linear_fin<<<1024, 256, 0, stream>>>(ws, out);
    k_cherry2<<<1024, 256, 0, stream>>>(ws, out);
  } else if (ws_size >= 4 * field_bytes) {
    // FAST: round-4 verified pipeline.
    k_weight6<<<4096, 256, 0, stream>>>(x, a1, a2, a3, a1p, a2p, a3p, ws, out);
    k_colscan_rev<<<128, 256, 0, stream>>>(ws);
    k_colscan_rev<<<256, 256, 0, stream>>>(ws + 2ull * NF);
    k_row_v2<<<8192, 256, 0, stream>>>(ws, ws + NF);
    k_colscan_fwd<<<128, 256, 0, stream>>>(ws);
    k_final_linear<<<8192, 256, 0, stream>>>(ws, out);
    k_cherry<<<8192, 256, 0, stream>>>(ws + 2ull * NF, ws + 3ull * NF, out);
  } else {
    // SAFE: 2 scratch fields, two x-passes.
    float* ws0 = ws;
    float* ws1 = ws + NF;
    k_weight3<<<4096, 256, 0, stream>>>(x, a1, a3, a2, ws0, ws1, out, 0);
    k_colscan_rev<<<128, 256, 0, stream>>>(ws0);
    k_row_v2<<<8192, 256, 0, stream>>>(ws0, ws1);
    k_colscan_fwd<<<128, 256, 0, stream>>>(ws0);
    k_final_linear<<<8192, 256, 0, stream>>>(ws0, out);
    k_weight3<<<4096, 256, 0, stream>>>(x, a1p, a3p, a2p, ws0, ws1, out, 8);
    k_colscan_rev<<<256, 256, 0, stream>>>(ws0);
    k_cherry<<<8192, 256, 0, stream>>>(ws0, ws1, out);
  }
}